// Round 2
// baseline (363.128 us; speedup 1.0000x reference)
//
#include <hip/hip_runtime.h>

// B = 1048576 rows, D = 64. xc = [x, sin(x)] (width 128).
// out[row] = { xc . w_sum + b,  exp2( log2|xc| . w_prod ) }
//
// Layout: 8 lanes per row; lane q = tid&7 owns x-cols [4q..4q+3] and
// [32+4q..32+4q+3] via two float4 loads (every 128B L2 line touched exactly
// once per wave). 3-stage __shfl_xor reduction, lane q==0 stores float2.
// Weights live in registers (no LDS, no barrier). 32-bit indexing throughout.

#define BLOCK 256
#define ITER 4

__global__ __launch_bounds__(BLOCK) void fb_kernel(
    const float4* __restrict__ x4,
    const float4* __restrict__ wsum4,
    const float*  __restrict__ b_sum,
    const float4* __restrict__ wprod4,
    float2*       __restrict__ out)
{
    const int tid = threadIdx.x;
    const int q   = tid & 7;

    // w[0..15] = x-part (cols 0..63), w[16..31] = sin-part (cols 64..127), float4 units
    const float4 wsA = wsum4[q];        // x cols 4q..4q+3
    const float4 wsB = wsum4[8 + q];    // x cols 32+4q..
    const float4 wsC = wsum4[16 + q];   // sin cols 4q..
    const float4 wsD = wsum4[24 + q];   // sin cols 32+4q..
    const float4 wpA = wprod4[q];
    const float4 wpB = wprod4[8 + q];
    const float4 wpC = wprod4[16 + q];
    const float4 wpD = wprod4[24 + q];
    const float  bias = b_sum[0];

    const int stride = gridDim.x * BLOCK;      // slice units (8 slices per row)
    int g = blockIdx.x * BLOCK + tid;

#pragma unroll
    for (int it = 0; it < ITER; ++it, g += stride) {
        const int row  = g >> 3;               // g ≡ tid (mod 8), stride % 8 == 0
        const int base = row * 16 + q;         // float4 index within x
        const float4 va = x4[base];            // cols 4q..4q+3
        const float4 vb = x4[base + 8];        // cols 32+4q..

        float s = 0.f;   // sum-head partial
        float p = 0.f;   // product-head partial (base-2 log domain)

#define ELEM(X, WS, WSS, WP, WPS)                            \
        {                                                    \
            const float xx = (X);                            \
            const float sx = __sinf(xx);                     \
            s = fmaf(xx, (WS),  s);                          \
            s = fmaf(sx, (WSS), s);                          \
            p = fmaf(__log2f(fabsf(xx)), (WP),  p);          \
            p = fmaf(__log2f(fabsf(sx)), (WPS), p);          \
        }

        ELEM(va.x, wsA.x, wsC.x, wpA.x, wpC.x)
        ELEM(va.y, wsA.y, wsC.y, wpA.y, wpC.y)
        ELEM(va.z, wsA.z, wsC.z, wpA.z, wpC.z)
        ELEM(va.w, wsA.w, wsC.w, wpA.w, wpC.w)
        ELEM(vb.x, wsB.x, wsD.x, wpB.x, wpD.x)
        ELEM(vb.y, wsB.y, wsD.y, wpB.y, wpD.y)
        ELEM(vb.z, wsB.z, wsD.z, wpB.z, wpD.z)
        ELEM(vb.w, wsB.w, wsD.w, wpB.w, wpD.w)
#undef ELEM

        // reduce across the 8 lanes owning this row
#pragma unroll
        for (int off = 4; off > 0; off >>= 1) {
            s += __shfl_xor(s, off);
            p += __shfl_xor(p, off);
        }

        if (q == 0) {
            // exp(sum ln) == exp2(sum log2); v_exp_f32 is native exp2
            out[row] = make_float2(s + bias, __builtin_amdgcn_exp2f(p));
        }
    }
}

extern "C" void kernel_launch(void* const* d_in, const int* in_sizes, int n_in,
                              void* d_out, int out_size, void* d_ws, size_t ws_size,
                              hipStream_t stream)
{
    const float4* x4     = (const float4*)d_in[0];
    const float4* wsum4  = (const float4*)d_in[1];
    const float*  b_sum  = (const float*)d_in[2];
    const float4* wprod4 = (const float4*)d_in[3];
    float2*       out    = (float2*)d_out;

    const long rows   = (long)in_sizes[0] / 64;            // 1,048,576
    const int  blocks = (int)(rows * 8 / (BLOCK * ITER));  // 8192 (exact)

    hipLaunchKernelGGL(fb_kernel, dim3(blocks), dim3(BLOCK), 0, stream,
                       x4, wsum4, b_sum, wprod4, out);
}

// Round 4
// 340.456 us; speedup vs baseline: 1.0666x; 1.0666x over previous
//
#include <hip/hip_runtime.h>

// B = 1048576 rows, D = 64. xc = [x, sin(x)] (width 128).
// out[row] = { xc . w_sum + b,  exp2( log2|xc| . w_prod ) }
//
// 8 lanes per row; lane q = tid&7 owns x-cols [4q..4q+3] and [32+4q..32+4q+3].
// ITER=8 rows-strided per thread; ALL 16 float4 loads issued up front
// (nontemporal) so 16 dwordx4 stay in flight -> latency hiding without
// relying on the compiler hoisting past the divergent stores.
//
// nontemporal builtins need clang-native vectors, not HIP_vector_type.

typedef float vf4 __attribute__((ext_vector_type(4)));
typedef float vf2 __attribute__((ext_vector_type(2)));

#define BLOCK 256
#define ITER 8

__global__ __launch_bounds__(BLOCK) void fb_kernel(
    const vf4* __restrict__ x4,
    const vf4* __restrict__ wsum4,
    const float* __restrict__ b_sum,
    const vf4* __restrict__ wprod4,
    vf2*       __restrict__ out)
{
    const int tid = threadIdx.x;
    const int q   = tid & 7;

    // w[0..15] = x-part (cols 0..63), w[16..31] = sin-part, float4 units
    const vf4 wsA = wsum4[q];
    const vf4 wsB = wsum4[8 + q];
    const vf4 wsC = wsum4[16 + q];
    const vf4 wsD = wsum4[24 + q];
    const vf4 wpA = wprod4[q];
    const vf4 wpB = wprod4[8 + q];
    const vf4 wpC = wprod4[16 + q];
    const vf4 wpD = wprod4[24 + q];
    const float bias = b_sum[0];

    const int stride = gridDim.x * BLOCK;      // slice units (8 per row)
    const int g0     = blockIdx.x * BLOCK + tid;

    // ---- issue all loads first (nontemporal: pure streaming, no reuse) ----
    vf4 va[ITER], vb[ITER];
    int row[ITER];
#pragma unroll
    for (int it = 0; it < ITER; ++it) {
        const int g    = g0 + it * stride;
        row[it]        = g >> 3;               // g ≡ tid (mod 8)
        const int base = row[it] * 16 + q;
        va[it] = __builtin_nontemporal_load(&x4[base]);
        vb[it] = __builtin_nontemporal_load(&x4[base + 8]);
    }

    // ---- compute + reduce + store per row ----
#pragma unroll
    for (int it = 0; it < ITER; ++it) {
        float s = 0.f;   // sum-head partial
        float p = 0.f;   // product-head partial (base-2 log domain)

#define ELEM(X, WS, WSS, WP, WPS)                            \
        {                                                    \
            const float xx = (X);                            \
            const float sx = __sinf(xx);                     \
            s = fmaf(xx, (WS),  s);                          \
            s = fmaf(sx, (WSS), s);                          \
            p = fmaf(__log2f(fabsf(xx)), (WP),  p);          \
            p = fmaf(__log2f(fabsf(sx)), (WPS), p);          \
        }

        ELEM(va[it].x, wsA.x, wsC.x, wpA.x, wpC.x)
        ELEM(va[it].y, wsA.y, wsC.y, wpA.y, wpC.y)
        ELEM(va[it].z, wsA.z, wsC.z, wpA.z, wpC.z)
        ELEM(va[it].w, wsA.w, wsC.w, wpA.w, wpC.w)
        ELEM(vb[it].x, wsB.x, wsD.x, wpB.x, wpD.x)
        ELEM(vb[it].y, wsB.y, wsD.y, wpB.y, wpD.y)
        ELEM(vb[it].z, wsB.z, wsD.z, wpB.z, wpD.z)
        ELEM(vb[it].w, wsB.w, wsD.w, wpB.w, wpD.w)
#undef ELEM

#pragma unroll
        for (int off = 4; off > 0; off >>= 1) {
            s += __shfl_xor(s, off);
            p += __shfl_xor(p, off);
        }

        if (q == 0) {
            // exp(sum ln) == exp2(sum log2); v_exp_f32 is native exp2
            vf2 r;
            r.x = s + bias;
            r.y = __builtin_amdgcn_exp2f(p);
            __builtin_nontemporal_store(r, &out[row[it]]);
        }
    }
}

extern "C" void kernel_launch(void* const* d_in, const int* in_sizes, int n_in,
                              void* d_out, int out_size, void* d_ws, size_t ws_size,
                              hipStream_t stream)
{
    const vf4*  x4     = (const vf4*)d_in[0];
    const vf4*  wsum4  = (const vf4*)d_in[1];
    const float* b_sum = (const float*)d_in[2];
    const vf4*  wprod4 = (const vf4*)d_in[3];
    vf2*        out    = (vf2*)d_out;

    const long rows   = (long)in_sizes[0] / 64;            // 1,048,576
    const int  blocks = (int)(rows * 8 / (BLOCK * ITER));  // 4096 (exact)

    hipLaunchKernelGGL(fb_kernel, dim3(blocks), dim3(BLOCK), 0, stream,
                       x4, wsum4, b_sum, wprod4, out);
}

// Round 5
// 338.061 us; speedup vs baseline: 1.0742x; 1.0071x over previous
//
#include <hip/hip_runtime.h>

// B = 1048576 rows, D = 64. xc = [x, sin(x)] (width 128).
// out[row] = { xc . w_sum + b,  exp2( log2|xc| . w_prod ) }
//
// 8 lanes per row; lane q = tid&7 owns x-cols [4q..4q+3] and [32+4q..32+4q+3].
// ITER=8 rows-strided per thread; ALL 16 float4 loads issued up front
// (nontemporal) so 16 dwordx4 stay in flight.
//
// R5 changes: __launch_bounds__(256,4) forces VGPR<=128 (4 waves/SIMD) so
// burst-phase memory idle is covered by more resident waves; sin computed as
// raw v_sin_f32 (input in revolutions, x*(1/2pi)) skipping the v_fract range
// reduction -- valid since |x| ~ N(0,1) stays far inside v_sin's domain.

typedef float vf4 __attribute__((ext_vector_type(4)));
typedef float vf2 __attribute__((ext_vector_type(2)));

#define BLOCK 256
#define ITER 8
#define INV_2PI 0.15915494309189535f

__global__ __launch_bounds__(BLOCK, 4) void fb_kernel(
    const vf4* __restrict__ x4,
    const vf4* __restrict__ wsum4,
    const float* __restrict__ b_sum,
    const vf4* __restrict__ wprod4,
    vf2*       __restrict__ out)
{
    const int tid = threadIdx.x;
    const int q   = tid & 7;

    // w[0..15] = x-part (cols 0..63), w[16..31] = sin-part, float4 units
    const vf4 wsA = wsum4[q];
    const vf4 wsB = wsum4[8 + q];
    const vf4 wsC = wsum4[16 + q];
    const vf4 wsD = wsum4[24 + q];
    const vf4 wpA = wprod4[q];
    const vf4 wpB = wprod4[8 + q];
    const vf4 wpC = wprod4[16 + q];
    const vf4 wpD = wprod4[24 + q];
    const float bias = b_sum[0];

    const int stride = gridDim.x * BLOCK;      // slice units (8 per row)
    const int g0     = blockIdx.x * BLOCK + tid;

    // ---- issue all loads first (nontemporal: pure streaming, no reuse) ----
    vf4 va[ITER], vb[ITER];
    int row[ITER];
#pragma unroll
    for (int it = 0; it < ITER; ++it) {
        const int g    = g0 + it * stride;
        row[it]        = g >> 3;               // g ≡ tid (mod 8)
        const int base = row[it] * 16 + q;
        va[it] = __builtin_nontemporal_load(&x4[base]);
        vb[it] = __builtin_nontemporal_load(&x4[base + 8]);
    }

    // ---- compute + reduce + store per row ----
#pragma unroll
    for (int it = 0; it < ITER; ++it) {
        float s = 0.f;   // sum-head partial
        float p = 0.f;   // product-head partial (base-2 log domain)

#define ELEM(X, WS, WSS, WP, WPS)                            \
        {                                                    \
            const float xx = (X);                            \
            const float sx = __builtin_amdgcn_sinf(xx * INV_2PI); \
            s = fmaf(xx, (WS),  s);                          \
            s = fmaf(sx, (WSS), s);                          \
            p = fmaf(__log2f(fabsf(xx)), (WP),  p);          \
            p = fmaf(__log2f(fabsf(sx)), (WPS), p);          \
        }

        ELEM(va[it].x, wsA.x, wsC.x, wpA.x, wpC.x)
        ELEM(va[it].y, wsA.y, wsC.y, wpA.y, wpC.y)
        ELEM(va[it].z, wsA.z, wsC.z, wpA.z, wpC.z)
        ELEM(va[it].w, wsA.w, wsC.w, wpA.w, wpC.w)
        ELEM(vb[it].x, wsB.x, wsD.x, wpB.x, wpD.x)
        ELEM(vb[it].y, wsB.y, wsD.y, wpB.y, wpD.y)
        ELEM(vb[it].z, wsB.z, wsD.z, wpB.z, wpD.z)
        ELEM(vb[it].w, wsB.w, wsD.w, wpB.w, wpD.w)
#undef ELEM

#pragma unroll
        for (int off = 4; off > 0; off >>= 1) {
            s += __shfl_xor(s, off);
            p += __shfl_xor(p, off);
        }

        if (q == 0) {
            // exp(sum ln) == exp2(sum log2); v_exp_f32 is native exp2
            vf2 r;
            r.x = s + bias;
            r.y = __builtin_amdgcn_exp2f(p);
            __builtin_nontemporal_store(r, &out[row[it]]);
        }
    }
}

extern "C" void kernel_launch(void* const* d_in, const int* in_sizes, int n_in,
                              void* d_out, int out_size, void* d_ws, size_t ws_size,
                              hipStream_t stream)
{
    const vf4*  x4     = (const vf4*)d_in[0];
    const vf4*  wsum4  = (const vf4*)d_in[1];
    const float* b_sum = (const float*)d_in[2];
    const vf4*  wprod4 = (const vf4*)d_in[3];
    vf2*        out    = (vf2*)d_out;

    const long rows   = (long)in_sizes[0] / 64;            // 1,048,576
    const int  blocks = (int)(rows * 8 / (BLOCK * ITER));  // 4096 (exact)

    hipLaunchKernelGGL(fb_kernel, dim3(blocks), dim3(BLOCK), 0, stream,
                       x4, wsum4, b_sum, wprod4, out);
}